// Round 1
// baseline (673.901 us; speedup 1.0000x reference)
//
#include <hip/hip_runtime.h>
#include <math.h>

#define B_ 16
#define N_ 16384
#define R_ 1024
#define D_ 320
#define BINS_ 32
#define H_ 512
#define EPS_ 1e-5f
#define AP 516   // padded LDS stride for A (2-way conflict max -> free)
#define EP 260   // padded LDS stride for E

// seg_off[g] = lower_bound(seg_ids, g), g in [0, R]; seg_ids is sorted.
__global__ void k_segoff(const int* __restrict__ seg, int* __restrict__ off){
  int g = blockIdx.x * blockDim.x + threadIdx.x;
  if (g > R_) return;
  int lo = 0, hi = N_;
  while (lo < hi){ int mid = (lo + hi) >> 1; if (seg[mid] < g) lo = mid + 1; else hi = mid; }
  off[g] = lo;
}

// Fold BN into W2:  out = relu(z)@W2f + bias3,  W2f[h][j]=c[h]*W2[h][j],
// bias3[j] = b2[j] + sum_h (beta[h]-mean[h]*c[h])*W2[h][j],  c = gamma*rsqrt(var+eps)
__global__ __launch_bounds__(512) void k_fold(const float* __restrict__ gamma, const float* __restrict__ beta,
                       const float* __restrict__ mean, const float* __restrict__ var,
                       const float* __restrict__ W2, const float* __restrict__ b2,
                       float* __restrict__ W2f, float* __restrict__ bias3){
  __shared__ float red[3 * H_];
  int h = threadIdx.x;
  float c = gamma[h] / sqrtf(var[h] + EPS_);
  float d = beta[h] - mean[h] * c;
  #pragma unroll
  for (int j = 0; j < 3; j++){
    float w = W2[h * 3 + j];
    W2f[h * 3 + j] = c * w;
    red[j * H_ + h] = d * w;
  }
  __syncthreads();
  for (int s = H_ / 2; s > 0; s >>= 1){
    if (h < s){
      #pragma unroll
      for (int j = 0; j < 3; j++) red[j * H_ + h] += red[j * H_ + h + s];
    }
    __syncthreads();
  }
  if (h < 3) bias3[h] = b2[h] + red[h * H_];
}

// One block per (segment r, batch b). 320 threads = one d each.
// pooled[b,r,k] = (sum_{n in seg} sum_{d in bin k} x[b,n,d]) / (max(cnt,1)*10)
__global__ __launch_bounds__(320) void k_pool(const float* __restrict__ x, const int* __restrict__ off,
                                              float* __restrict__ pooled){
  int r = blockIdx.x, b = blockIdx.y;
  int s = off[r], e = off[r + 1];
  __shared__ float lds[D_];
  float acc = 0.f;
  const float* xp = x + ((size_t)b * N_) * D_ + threadIdx.x;
  for (int i = s; i < e; i++) acc += xp[(size_t)i * D_];
  lds[threadIdx.x] = acc;
  __syncthreads();
  if (threadIdx.x < BINS_){
    float ssum = 0.f;
    #pragma unroll
    for (int j = 0; j < 10; j++) ssum += lds[threadIdx.x * 10 + j];
    int cnt = e - s;
    float scale = 1.0f / (float)((cnt > 0 ? cnt : 1) * 10);
    pooled[((size_t)(b * R_ + r)) * BINS_ + threadIdx.x] = ssum * scale;
  }
}

// One block per segment. A[b][h] = pooled[b,r,:]@W1[:32,h] + b1[h] staged in LDS (all 16 b).
// Per 16-atom tile: E[a][h] = cond[n]@W1[32:35,h] staged per 256-h chunk; each thread owns
// one (atom, b) pair and accumulates the 3-wide W2f dot over h.
__global__ __launch_bounds__(256) void k_main(const float* __restrict__ pooled, const float* __restrict__ cond,
                      const float* __restrict__ W1, const float* __restrict__ b1,
                      const int* __restrict__ off, const float* __restrict__ W2f,
                      const float* __restrict__ bias3, float* __restrict__ out){
  __shared__ __align__(16) float P[B_ * BINS_];
  __shared__ __align__(16) float A[B_ * AP];
  __shared__ __align__(16) float E[16 * EP];
  __shared__ float condT[16 * 3];
  int tid = threadIdx.x;
  int r = blockIdx.x;
  int s = off[r];
  int cnt = off[r + 1] - s;
  if (cnt == 0) return;   // uniform exit, before any sync

  for (int i = tid; i < B_ * BINS_; i += 256)
    P[i] = pooled[(size_t)((i >> 5) * R_ + r) * BINS_ + (i & 31)];
  __syncthreads();

  // A tile: each thread computes h = tid, tid+256 for all 16 b
  for (int h = tid; h < H_; h += 256){
    float bb = b1[h];
    float acc[B_];
    #pragma unroll
    for (int b = 0; b < B_; b++) acc[b] = bb;
    #pragma unroll
    for (int k = 0; k < BINS_; k++){
      float w = W1[k * H_ + h];            // coalesced; P broadcast
      #pragma unroll
      for (int b = 0; b < B_; b++) acc[b] += P[b * BINS_ + k] * w;
    }
    #pragma unroll
    for (int b = 0; b < B_; b++) A[b * AP + h] = acc[b];
  }

  int a = tid >> 4, b = tid & 15;
  for (int t0 = 0; t0 < cnt; t0 += 16){
    int na = min(16, cnt - t0);
    __syncthreads();                        // prior E-staging readers of condT done
    if (tid < 48){
      int aa = tid / 3, c = tid % 3;
      condT[tid] = (aa < na) ? cond[(size_t)(s + t0 + aa) * 3 + c] : 0.f;
    }
    __syncthreads();
    float o0 = 0.f, o1 = 0.f, o2 = 0.f;
    int ae = a < na ? a : 0;                // clamp: keep main loop non-divergent
    for (int hc = 0; hc < 2; hc++){
      int h = (hc << 8) + tid;
      float w0 = W1[32 * H_ + h], w1 = W1[33 * H_ + h], w2 = W1[34 * H_ + h];
      for (int aa = 0; aa < na; aa++)
        E[aa * EP + tid] = condT[aa * 3] * w0 + condT[aa * 3 + 1] * w1 + condT[aa * 3 + 2] * w2;
      __syncthreads();                      // also covers A write->read on first pass
      const float* Ap = &A[b * AP + (hc << 8)];
      const float* Ep = &E[ae * EP];
      const float* Wp = &W2f[(hc << 8) * 3];
      #pragma unroll 4
      for (int hp = 0; hp < 256; hp += 4){
        float4 av = *(const float4*)(Ap + hp);
        float4 ev = *(const float4*)(Ep + hp);
        const float* w = Wp + hp * 3;       // wave-uniform -> scalar loads
        float z;
        z = av.x + ev.x; z = fmaxf(z, 0.f); o0 = fmaf(z, w[0], o0); o1 = fmaf(z, w[1], o1); o2 = fmaf(z, w[2], o2);
        z = av.y + ev.y; z = fmaxf(z, 0.f); o0 = fmaf(z, w[3], o0); o1 = fmaf(z, w[4], o1); o2 = fmaf(z, w[5], o2);
        z = av.z + ev.z; z = fmaxf(z, 0.f); o0 = fmaf(z, w[6], o0); o1 = fmaf(z, w[7], o1); o2 = fmaf(z, w[8], o2);
        z = av.w + ev.w; z = fmaxf(z, 0.f); o0 = fmaf(z, w[9], o0); o1 = fmaf(z, w[10], o1); o2 = fmaf(z, w[11], o2);
      }
      __syncthreads();                      // protect E before next chunk/tile restage
    }
    if (a < na){
      size_t oi = ((size_t)b * N_ + (size_t)(s + t0 + a)) * 3;
      out[oi + 0] = o0 + bias3[0];
      out[oi + 1] = o1 + bias3[1];
      out[oi + 2] = o2 + bias3[2];
    }
  }
}

extern "C" void kernel_launch(void* const* d_in, const int* in_sizes, int n_in,
                              void* d_out, int out_size, void* d_ws, size_t ws_size,
                              hipStream_t stream) {
  const float* x      = (const float*)d_in[0];
  const float* cond   = (const float*)d_in[1];
  const int*   seg    = (const int*)  d_in[2];
  const float* W1     = (const float*)d_in[3];
  const float* b1     = (const float*)d_in[4];
  const float* gamma  = (const float*)d_in[5];
  const float* beta   = (const float*)d_in[6];
  const float* bnmean = (const float*)d_in[7];
  const float* bnvar  = (const float*)d_in[8];
  const float* W2     = (const float*)d_in[9];
  const float* b2     = (const float*)d_in[10];
  float* out = (float*)d_out;

  char* ws = (char*)d_ws;
  int*   seg_off = (int*)ws;                    // 1025 ints
  float* W2f     = (float*)(ws + 8192);         // 1536 floats
  float* bias3   = (float*)(ws + 14592);        // 3 floats
  float* pooled  = (float*)(ws + 16384);        // B*R*32 floats = 2 MB

  k_segoff<<<dim3(5), dim3(256), 0, stream>>>(seg, seg_off);
  k_fold<<<dim3(1), dim3(512), 0, stream>>>(gamma, beta, bnmean, bnvar, W2, b2, W2f, bias3);
  k_pool<<<dim3(R_, B_), dim3(320), 0, stream>>>(x, seg_off, pooled);
  k_main<<<dim3(R_), dim3(256), 0, stream>>>(pooled, cond, W1, b1, seg_off, W2f, bias3, out);
}

// Round 2
// 638.795 us; speedup vs baseline: 1.0550x; 1.0550x over previous
//
#include <hip/hip_runtime.h>
#include <math.h>

#define B_ 16
#define N_ 16384
#define R_ 1024
#define D_ 320
#define BINS_ 32
#define H_ 512
#define EPS_ 1e-5f
#define AP 516   // padded LDS stride for A (2-way conflict max -> free)
#define EP 260   // padded LDS stride for E

// Fused prep: blocks 0-4 segment offsets (binary search on sorted seg_ids),
// block 5 BN->W2 fold, blocks 6-37 zero the pooled accumulator.
__global__ __launch_bounds__(256) void k_prep(const int* __restrict__ seg,
                      const float* __restrict__ gamma, const float* __restrict__ beta,
                      const float* __restrict__ mean, const float* __restrict__ var,
                      const float* __restrict__ W2, const float* __restrict__ b2,
                      int* __restrict__ off, float* __restrict__ W2f,
                      float* __restrict__ bias3, float* __restrict__ pooled){
  __shared__ float red[3 * 256];
  int blk = blockIdx.x, tid = threadIdx.x;
  if (blk < 5){
    int g = blk * 256 + tid;
    if (g <= R_){
      int lo = 0, hi = N_;
      while (lo < hi){ int mid = (lo + hi) >> 1; if (seg[mid] < g) lo = mid + 1; else hi = mid; }
      off[g] = lo;
    }
  } else if (blk == 5){
    float p0 = 0.f, p1 = 0.f, p2 = 0.f;
    for (int h = tid; h < H_; h += 256){
      float c = gamma[h] / sqrtf(var[h] + EPS_);
      float d = beta[h] - mean[h] * c;
      float w0 = W2[h * 3 + 0], w1 = W2[h * 3 + 1], w2 = W2[h * 3 + 2];
      W2f[h * 3 + 0] = c * w0; W2f[h * 3 + 1] = c * w1; W2f[h * 3 + 2] = c * w2;
      p0 += d * w0; p1 += d * w1; p2 += d * w2;
    }
    red[tid] = p0; red[256 + tid] = p1; red[512 + tid] = p2;
    __syncthreads();
    for (int s = 128; s > 0; s >>= 1){
      if (tid < s){
        red[tid] += red[tid + s];
        red[256 + tid] += red[256 + tid + s];
        red[512 + tid] += red[512 + tid + s];
      }
      __syncthreads();
    }
    if (tid < 3) bias3[tid] = b2[tid] + red[tid * 256];
  } else {
    float4 z = {0.f, 0.f, 0.f, 0.f};
    float4* p4 = (float4*)pooled;
    const int total4 = B_ * R_ * BINS_ / 4;           // 131072
    for (int i = (blk - 6) * 256 + tid; i < total4; i += 32 * 256) p4[i] = z;
  }
}

// One block per (64-row chunk c, batch b). 320 threads; thread = (rowoff 0..3, col4 0..79),
// float4 streaming loads. Segment runs within the chunk are block-uniform; at each run end,
// LDS-reduce 320 floats x 4 rowoffs into 32 bin sums and atomicAdd into pooled (raw sums).
__global__ __launch_bounds__(320) void k_pool(const float* __restrict__ x,
                                              const int* __restrict__ seg,
                                              float* __restrict__ pooled){
  __shared__ int sseg[64];
  __shared__ __align__(16) float red2[4 * 320];
  int c = blockIdx.x, b = blockIdx.y, tid = threadIdx.x;
  int base = c * 64;
  if (tid < 64) sseg[tid] = seg[base + tid];
  __syncthreads();
  int rowoff = tid / 80;          // 0..3
  int col4 = tid - rowoff * 80;   // 0..79
  const float4* xp = (const float4*)x + ((size_t)b * N_ + base) * 80 + col4;
  int i = 0;
  while (i < 64){
    int sg = sseg[i];
    int e = i + 1;
    while (e < 64 && sseg[e] == sg) e++;
    float4 acc = {0.f, 0.f, 0.f, 0.f};
    for (int r = i + rowoff; r < e; r += 4){
      float4 v = xp[(size_t)r * 80];
      acc.x += v.x; acc.y += v.y; acc.z += v.z; acc.w += v.w;
    }
    *(float4*)&red2[rowoff * 320 + col4 * 4] = acc;   // 16B-aligned b128 store
    __syncthreads();
    if (tid < 32){
      float s = 0.f;
      #pragma unroll
      for (int ro = 0; ro < 4; ro++)
        #pragma unroll
        for (int j = 0; j < 10; j++) s += red2[ro * 320 + tid * 10 + j];
      atomicAdd(&pooled[((size_t)b * R_ + sg) * BINS_ + tid], s);
    }
    __syncthreads();
    i = e;
  }
}

// One block per segment. A[b][h] = pooled_mean[b,r,:]@W1[:32,h] + b1[h] staged in LDS (all 16 b).
// Per 16-atom tile: E[a][h] = cond[n]@W1[32:35,h] staged per 256-h chunk; each thread owns
// one (atom, b) pair and accumulates the 3-wide folded-W2 dot over h.
__global__ __launch_bounds__(256) void k_main(const float* __restrict__ pooled, const float* __restrict__ cond,
                      const float* __restrict__ W1, const float* __restrict__ b1,
                      const int* __restrict__ off, const float* __restrict__ W2f,
                      const float* __restrict__ bias3, float* __restrict__ out){
  __shared__ __align__(16) float P[B_ * BINS_];
  __shared__ __align__(16) float A[B_ * AP];
  __shared__ __align__(16) float E[16 * EP];
  __shared__ float condT[16 * 3];
  int tid = threadIdx.x;
  int r = blockIdx.x;
  int s = off[r];
  int cnt = off[r + 1] - s;
  if (cnt == 0) return;   // uniform exit, before any sync

  float sc = 1.0f / (float)(cnt * 10);
  for (int i = tid; i < B_ * BINS_; i += 256)
    P[i] = pooled[(size_t)((i >> 5) * R_ + r) * BINS_ + (i & 31)] * sc;
  __syncthreads();

  // A tile: each thread computes h = tid, tid+256 for all 16 b
  for (int h = tid; h < H_; h += 256){
    float bb = b1[h];
    float acc[B_];
    #pragma unroll
    for (int b = 0; b < B_; b++) acc[b] = bb;
    #pragma unroll
    for (int k = 0; k < BINS_; k++){
      float w = W1[k * H_ + h];            // coalesced; P broadcast
      #pragma unroll
      for (int b = 0; b < B_; b++) acc[b] += P[b * BINS_ + k] * w;
    }
    #pragma unroll
    for (int b = 0; b < B_; b++) A[b * AP + h] = acc[b];
  }

  int a = tid >> 4, b = tid & 15;
  for (int t0 = 0; t0 < cnt; t0 += 16){
    int na = min(16, cnt - t0);
    __syncthreads();                        // prior E-staging readers of condT done
    if (tid < 48){
      int aa = tid / 3, cc = tid % 3;
      condT[tid] = (aa < na) ? cond[(size_t)(s + t0 + aa) * 3 + cc] : 0.f;
    }
    __syncthreads();
    float o0 = 0.f, o1 = 0.f, o2 = 0.f;
    int ae = a < na ? a : 0;                // clamp: keep main loop non-divergent
    for (int hc = 0; hc < 2; hc++){
      int h = (hc << 8) + tid;
      float w0 = W1[32 * H_ + h], w1 = W1[33 * H_ + h], w2 = W1[34 * H_ + h];
      for (int aa = 0; aa < na; aa++)
        E[aa * EP + tid] = condT[aa * 3] * w0 + condT[aa * 3 + 1] * w1 + condT[aa * 3 + 2] * w2;
      __syncthreads();                      // also covers A write->read on first pass
      const float* Ap = &A[b * AP + (hc << 8)];
      const float* Ep = &E[ae * EP];
      const float* Wp = &W2f[(hc << 8) * 3];
      #pragma unroll 4
      for (int hp = 0; hp < 256; hp += 4){
        float4 av = *(const float4*)(Ap + hp);
        float4 ev = *(const float4*)(Ep + hp);
        const float* w = Wp + hp * 3;       // wave-uniform -> scalar loads
        float z;
        z = av.x + ev.x; z = fmaxf(z, 0.f); o0 = fmaf(z, w[0], o0); o1 = fmaf(z, w[1], o1); o2 = fmaf(z, w[2], o2);
        z = av.y + ev.y; z = fmaxf(z, 0.f); o0 = fmaf(z, w[3], o0); o1 = fmaf(z, w[4], o1); o2 = fmaf(z, w[5], o2);
        z = av.z + ev.z; z = fmaxf(z, 0.f); o0 = fmaf(z, w[6], o0); o1 = fmaf(z, w[7], o1); o2 = fmaf(z, w[8], o2);
        z = av.w + ev.w; z = fmaxf(z, 0.f); o0 = fmaf(z, w[9], o0); o1 = fmaf(z, w[10], o1); o2 = fmaf(z, w[11], o2);
      }
      __syncthreads();                      // protect E before next chunk/tile restage
    }
    if (a < na){
      size_t oi = ((size_t)b * N_ + (size_t)(s + t0 + a)) * 3;
      out[oi + 0] = o0 + bias3[0];
      out[oi + 1] = o1 + bias3[1];
      out[oi + 2] = o2 + bias3[2];
    }
  }
}

extern "C" void kernel_launch(void* const* d_in, const int* in_sizes, int n_in,
                              void* d_out, int out_size, void* d_ws, size_t ws_size,
                              hipStream_t stream) {
  const float* x      = (const float*)d_in[0];
  const float* cond   = (const float*)d_in[1];
  const int*   seg    = (const int*)  d_in[2];
  const float* W1     = (const float*)d_in[3];
  const float* b1     = (const float*)d_in[4];
  const float* gamma  = (const float*)d_in[5];
  const float* beta   = (const float*)d_in[6];
  const float* bnmean = (const float*)d_in[7];
  const float* bnvar  = (const float*)d_in[8];
  const float* W2     = (const float*)d_in[9];
  const float* b2     = (const float*)d_in[10];
  float* out = (float*)d_out;

  char* ws = (char*)d_ws;
  int*   seg_off = (int*)ws;                    // 1025 ints
  float* W2f     = (float*)(ws + 8192);         // 1536 floats
  float* bias3   = (float*)(ws + 14592);        // 3 floats
  float* pooled  = (float*)(ws + 16384);        // B*R*32 floats = 2 MB (raw sums)

  k_prep<<<dim3(38), dim3(256), 0, stream>>>(seg, gamma, beta, bnmean, bnvar, W2, b2,
                                             seg_off, W2f, bias3, pooled);
  k_pool<<<dim3(N_ / 64, B_), dim3(320), 0, stream>>>(x, seg, pooled);
  k_main<<<dim3(R_), dim3(256), 0, stream>>>(pooled, cond, W1, b1, seg_off, W2f, bias3, out);
}

// Round 3
// 633.957 us; speedup vs baseline: 1.0630x; 1.0076x over previous
//
#include <hip/hip_runtime.h>
#include <math.h>

#define B_ 16
#define N_ 16384
#define R_ 1024
#define D_ 320
#define BINS_ 32
#define H_ 512
#define EPS_ 1e-5f
#define AP 516   // padded LDS stride for A (2-way conflict max -> free)
#define EP 260   // padded LDS stride for E

// Fused prep: blocks 0-4 segment offsets (binary search on sorted seg_ids),
// block 5 BN->W2 fold, blocks 6-37 zero the pooled accumulator.
__global__ __launch_bounds__(256) void k_prep(const int* __restrict__ seg,
                      const float* __restrict__ gamma, const float* __restrict__ beta,
                      const float* __restrict__ mean, const float* __restrict__ var,
                      const float* __restrict__ W2, const float* __restrict__ b2,
                      int* __restrict__ off, float* __restrict__ W2f,
                      float* __restrict__ bias3, float* __restrict__ pooled){
  __shared__ float red[3 * 256];
  int blk = blockIdx.x, tid = threadIdx.x;
  if (blk < 5){
    int g = blk * 256 + tid;
    if (g <= R_){
      int lo = 0, hi = N_;
      while (lo < hi){ int mid = (lo + hi) >> 1; if (seg[mid] < g) lo = mid + 1; else hi = mid; }
      off[g] = lo;
    }
  } else if (blk == 5){
    float p0 = 0.f, p1 = 0.f, p2 = 0.f;
    for (int h = tid; h < H_; h += 256){
      float c = gamma[h] / sqrtf(var[h] + EPS_);
      float d = beta[h] - mean[h] * c;
      float w0 = W2[h * 3 + 0], w1 = W2[h * 3 + 1], w2 = W2[h * 3 + 2];
      W2f[h * 3 + 0] = c * w0; W2f[h * 3 + 1] = c * w1; W2f[h * 3 + 2] = c * w2;
      p0 += d * w0; p1 += d * w1; p2 += d * w2;
    }
    red[tid] = p0; red[256 + tid] = p1; red[512 + tid] = p2;
    __syncthreads();
    for (int s = 128; s > 0; s >>= 1){
      if (tid < s){
        red[tid] += red[tid + s];
        red[256 + tid] += red[256 + tid + s];
        red[512 + tid] += red[512 + tid + s];
      }
      __syncthreads();
    }
    if (tid < 3) bias3[tid] = b2[tid] + red[tid * 256];
  } else {
    float4 z = {0.f, 0.f, 0.f, 0.f};
    float4* p4 = (float4*)pooled;
    const int total4 = B_ * R_ * BINS_ / 4;           // 131072
    for (int i = (blk - 6) * 256 + tid; i < total4; i += 32 * 256) p4[i] = z;
  }
}

// One WAVE per (64-row chunk, batch b) — no __syncthreads anywhere.
// Run boundaries from registers (shfl_up + ballot + ctz). Each lane holds 5
// column accumulators (cols lane, lane+64, ..., lane+256). Per run: flush to
// wave-local LDS, half-wave 10-read bin reduce (2-way bank alias = free),
// one coalesced 32-lane atomicAdd of raw sums into pooled.
__global__ __launch_bounds__(256) void k_pool(const float* __restrict__ x,
                                              const int* __restrict__ seg,
                                              float* __restrict__ pooled){
  __shared__ __align__(16) float red[4 * 320];
  int tid = threadIdx.x;
  int wid = tid >> 6, lane = tid & 63;
  int c = blockIdx.x * 4 + wid;        // 64-row chunk index
  int b = blockIdx.y;
  int base = c * 64;
  int my_seg = seg[base + lane];
  int prev = __shfl_up(my_seg, 1);
  bool bnd = (lane == 0) || (my_seg != prev);
  unsigned long long mask = __ballot(bnd);
  const float* xp = x + ((size_t)b * N_ + base) * D_ + lane;
  float* wred = &red[wid * 320];
  while (mask){
    int i = __builtin_ctzll(mask);
    mask &= mask - 1;
    int e = mask ? __builtin_ctzll(mask) : 64;
    int sg = __shfl(my_seg, i);
    float a0 = 0.f, a1 = 0.f, a2 = 0.f, a3 = 0.f, a4 = 0.f;
    const float* rp = xp + (size_t)i * D_;
    for (int r = i; r < e; r++, rp += D_){
      a0 += rp[0]; a1 += rp[64]; a2 += rp[128]; a3 += rp[192]; a4 += rp[256];
    }
    wred[lane] = a0; wred[64 + lane] = a1; wred[128 + lane] = a2;
    wred[192 + lane] = a3; wred[256 + lane] = a4;
    if (lane < 32){
      float s = 0.f;
      #pragma unroll
      for (int j = 0; j < 10; j++) s += wred[lane * 10 + j];
      atomicAdd(&pooled[((size_t)b * R_ + sg) * BINS_ + lane], s);
    }
  }
}

// One block per segment. A[b][h] = pooled_mean[b,r,:]@W1[:32,h] + b1[h] staged in LDS (all 16 b).
// Per 16-atom tile: E[a][h] = cond[n]@W1[32:35,h] staged per 256-h chunk; each thread owns
// one (atom, b) pair and accumulates the 3-wide folded-W2 dot over h.
__global__ __launch_bounds__(256) void k_main(const float* __restrict__ pooled, const float* __restrict__ cond,
                      const float* __restrict__ W1, const float* __restrict__ b1,
                      const int* __restrict__ off, const float* __restrict__ W2f,
                      const float* __restrict__ bias3, float* __restrict__ out){
  __shared__ __align__(16) float P[B_ * BINS_];
  __shared__ __align__(16) float A[B_ * AP];
  __shared__ __align__(16) float E[16 * EP];
  __shared__ float condT[16 * 3];
  int tid = threadIdx.x;
  int r = blockIdx.x;
  int s = off[r];
  int cnt = off[r + 1] - s;
  if (cnt == 0) return;   // uniform exit, before any sync

  float sc = 1.0f / (float)(cnt * 10);
  for (int i = tid; i < B_ * BINS_; i += 256)
    P[i] = pooled[(size_t)((i >> 5) * R_ + r) * BINS_ + (i & 31)] * sc;
  __syncthreads();

  // A tile: each thread computes h = tid, tid+256 for all 16 b
  for (int h = tid; h < H_; h += 256){
    float bb = b1[h];
    float acc[B_];
    #pragma unroll
    for (int b = 0; b < B_; b++) acc[b] = bb;
    #pragma unroll
    for (int k = 0; k < BINS_; k++){
      float w = W1[k * H_ + h];            // coalesced; P broadcast
      #pragma unroll
      for (int b = 0; b < B_; b++) acc[b] += P[b * BINS_ + k] * w;
    }
    #pragma unroll
    for (int b = 0; b < B_; b++) A[b * AP + h] = acc[b];
  }

  int a = tid >> 4, b = tid & 15;
  for (int t0 = 0; t0 < cnt; t0 += 16){
    int na = min(16, cnt - t0);
    __syncthreads();                        // prior E-staging readers of condT done
    if (tid < 48){
      int aa = tid / 3, cc = tid % 3;
      condT[tid] = (aa < na) ? cond[(size_t)(s + t0 + aa) * 3 + cc] : 0.f;
    }
    __syncthreads();
    float o0 = 0.f, o1 = 0.f, o2 = 0.f;
    int ae = a < na ? a : 0;                // clamp: keep main loop non-divergent
    for (int hc = 0; hc < 2; hc++){
      int h = (hc << 8) + tid;
      float w0 = W1[32 * H_ + h], w1 = W1[33 * H_ + h], w2 = W1[34 * H_ + h];
      for (int aa = 0; aa < na; aa++)
        E[aa * EP + tid] = condT[aa * 3] * w0 + condT[aa * 3 + 1] * w1 + condT[aa * 3 + 2] * w2;
      __syncthreads();                      // also covers A write->read on first pass
      const float* Ap = &A[b * AP + (hc << 8)];
      const float* Ep = &E[ae * EP];
      const float* Wp = &W2f[(hc << 8) * 3];
      #pragma unroll 4
      for (int hp = 0; hp < 256; hp += 4){
        float4 av = *(const float4*)(Ap + hp);
        float4 ev = *(const float4*)(Ep + hp);
        const float* w = Wp + hp * 3;       // wave-uniform -> scalar loads
        float z;
        z = av.x + ev.x; z = fmaxf(z, 0.f); o0 = fmaf(z, w[0], o0); o1 = fmaf(z, w[1], o1); o2 = fmaf(z, w[2], o2);
        z = av.y + ev.y; z = fmaxf(z, 0.f); o0 = fmaf(z, w[3], o0); o1 = fmaf(z, w[4], o1); o2 = fmaf(z, w[5], o2);
        z = av.z + ev.z; z = fmaxf(z, 0.f); o0 = fmaf(z, w[6], o0); o1 = fmaf(z, w[7], o1); o2 = fmaf(z, w[8], o2);
        z = av.w + ev.w; z = fmaxf(z, 0.f); o0 = fmaf(z, w[9], o0); o1 = fmaf(z, w[10], o1); o2 = fmaf(z, w[11], o2);
      }
      __syncthreads();                      // protect E before next chunk/tile restage
    }
    if (a < na){
      size_t oi = ((size_t)b * N_ + (size_t)(s + t0 + a)) * 3;
      out[oi + 0] = o0 + bias3[0];
      out[oi + 1] = o1 + bias3[1];
      out[oi + 2] = o2 + bias3[2];
    }
  }
}

extern "C" void kernel_launch(void* const* d_in, const int* in_sizes, int n_in,
                              void* d_out, int out_size, void* d_ws, size_t ws_size,
                              hipStream_t stream) {
  const float* x      = (const float*)d_in[0];
  const float* cond   = (const float*)d_in[1];
  const int*   seg    = (const int*)  d_in[2];
  const float* W1     = (const float*)d_in[3];
  const float* b1     = (const float*)d_in[4];
  const float* gamma  = (const float*)d_in[5];
  const float* beta   = (const float*)d_in[6];
  const float* bnmean = (const float*)d_in[7];
  const float* bnvar  = (const float*)d_in[8];
  const float* W2     = (const float*)d_in[9];
  const float* b2     = (const float*)d_in[10];
  float* out = (float*)d_out;

  char* ws = (char*)d_ws;
  int*   seg_off = (int*)ws;                    // 1025 ints
  float* W2f     = (float*)(ws + 8192);         // 1536 floats
  float* bias3   = (float*)(ws + 14592);        // 3 floats
  float* pooled  = (float*)(ws + 16384);        // B*R*32 floats = 2 MB (raw sums)

  k_prep<<<dim3(38), dim3(256), 0, stream>>>(seg, gamma, beta, bnmean, bnvar, W2, b2,
                                             seg_off, W2f, bias3, pooled);
  k_pool<<<dim3(N_ / 64 / 4, B_), dim3(256), 0, stream>>>(x, seg, pooled);
  k_main<<<dim3(R_), dim3(256), 0, stream>>>(pooled, cond, W1, b1, seg_off, W2f, bias3, out);
}